// Round 9
// baseline (319.736 us; speedup 1.0000x reference)
//
#include <hip/hip_runtime.h>

typedef unsigned short ushort_t;
typedef __attribute__((ext_vector_type(8))) short short8;
typedef __attribute__((ext_vector_type(8))) __bf16 bf16x8;
typedef __attribute__((ext_vector_type(4))) float floatx4;

#define NN 96
#define DD 64
#define BSZ 16
#define TSTEP 12
#define ITILES 6
#define NTILE (BSZ*ITILES)   /* 96 tiles */

// workspace offsets (bytes)
#define OFF_HALL  0u           /* 13 slots * 393216 = 5111808 (slot 0 unused) */
#define OFF_E     5111808u     /* 73728 */
#define OFF_SG    5185536u     /* 2 parity slots * 393216 = 786432 */
#define OFF_WSWZ  5971968u     /* 73728 */
#define OFF_FLAG  6045696u     /* 12*96*4 = 4608 */
#define HSLOT     98304        /* floats per hidden/S slot */

union fragU  { short8 s; bf16x8 b; };
union packU  { floatx4 f; unsigned long long u[2]; };

static __device__ __forceinline__ short f2bf(float f){
    union { float f; unsigned u; } v; v.f = f;
    unsigned u = v.u;
    u += 0x7fffu + ((u >> 16) & 1u);   // RNE
    return (short)(u >> 16);
}
// inputs provably bounded (|h|<=1, 0.05-scale weights) -> no clamps needed
static __device__ __forceinline__ float fast_tanh(float x){
    float p = __expf(2.f * x);
    return (p - 1.f) * __builtin_amdgcn_rcpf(p + 1.f);
}
static __device__ __forceinline__ float fast_sigmoid(float x){
    float p = __expf(-x);
    return __builtin_amdgcn_rcpf(1.f + p);
}
static __device__ __forceinline__ void zero4(floatx4* a){
    floatx4 z = {0.f,0.f,0.f,0.f};
    a[0]=z; a[1]=z; a[2]=z; a[3]=z;
}
// agent-scope (device-coherent) 16B load/store — R6-validated handoff primitive
static __device__ __forceinline__ floatx4 aload4(const float* p){
    const unsigned long long* s = (const unsigned long long*)p;
    packU pk;
    pk.u[0] = __hip_atomic_load(s,     __ATOMIC_RELAXED, __HIP_MEMORY_SCOPE_AGENT);
    pk.u[1] = __hip_atomic_load(s + 1, __ATOMIC_RELAXED, __HIP_MEMORY_SCOPE_AGENT);
    return pk.f;
}
static __device__ __forceinline__ void astore4(float* p, floatx4 v){
    unsigned long long* d = (unsigned long long*)p;
    packU pk; pk.f = v;
    __hip_atomic_store(d,     pk.u[0], __ATOMIC_RELAXED, __HIP_MEMORY_SCOPE_AGENT);
    __hip_atomic_store(d + 1, pk.u[1], __ATOMIC_RELAXED, __HIP_MEMORY_SCOPE_AGENT);
}
// read A-fragments (16x64, row m = lane&15, k = quad*8+jj) from LDS tile stride 68
static __device__ __forceinline__ void buildA(const float* sM, int col, int quad, short8& a0, short8& a1){
    floatx4 f0 = *(const floatx4*)&sM[col*68 + quad*8];
    floatx4 f1 = *(const floatx4*)&sM[col*68 + quad*8 + 4];
    floatx4 f2 = *(const floatx4*)&sM[col*68 + 32 + quad*8];
    floatx4 f3 = *(const floatx4*)&sM[col*68 + 32 + quad*8 + 4];
    fragU u0, u1;
    #pragma unroll
    for (int jj = 0; jj < 4; jj++){
        u0.b[jj]   = (__bf16)f0[jj];
        u0.b[4+jj] = (__bf16)f1[jj];
        u1.b[jj]   = (__bf16)f2[jj];
        u1.b[4+jj] = (__bf16)f3[jj];
    }
    a0 = u0.s; a1 = u1.s;
}
// 16x64 = (16x64) @ (64x64), B pre-swizzled fragment-major
static __device__ __forceinline__ void mm16(short8 a0, short8 a1, const short8* wzm, int l, floatx4* acc){
    #pragma unroll
    for (int nt = 0; nt < 4; nt++){
        short8 b0 = wzm[nt*64 + l];
        short8 b1 = wzm[(4 + nt)*64 + l];
        acc[nt] = __builtin_amdgcn_mfma_f32_16x16x32_bf16(a0, b0, acc[nt], 0, 0, 0);
        acc[nt] = __builtin_amdgcn_mfma_f32_16x16x32_bf16(a1, b1, acc[nt], 0, 0, 0);
    }
}
// mm16 with preloaded B fragments
static __device__ __forceinline__ void mm16r(short8 a0, short8 a1, const short8* f, floatx4* acc){
    #pragma unroll
    for (int nt = 0; nt < 4; nt++){
        acc[nt] = __builtin_amdgcn_mfma_f32_16x16x32_bf16(a0, f[nt],     acc[nt], 0, 0, 0);
        acc[nt] = __builtin_amdgcn_mfma_f32_16x16x32_bf16(a1, f[4 + nt], acc[nt], 0, 0, 0);
    }
}

// ---------------------------------------------------------------------------
// init: zero flags, compute E_* = emb @ W_i* + b_*, pre-swizzle 9 weight
// matrices into bf16 B-fragment order. grid 216 = 72(E) + 144(swizzle).
// ---------------------------------------------------------------------------
__global__ __launch_bounds__(256) void k_init(
    const float* __restrict__ emb, const float* __restrict__ Wmsg1,
    const float* __restrict__ Wmsg2,
    const float* __restrict__ Whr, const float* __restrict__ Whi, const float* __restrict__ Whh,
    const float* __restrict__ Wir, const float* __restrict__ bir,
    const float* __restrict__ Wii, const float* __restrict__ bii,
    const float* __restrict__ Win, const float* __restrict__ bin,
    const float* __restrict__ Wo1, const float* __restrict__ Wo2, const float* __restrict__ Wo3,
    int* __restrict__ flagv, float* __restrict__ Ef, ushort_t* __restrict__ wswz)
{
    int wg = blockIdx.x, tid = threadIdx.x;
    if (wg < 72) {                        // E matrices: 3 * 96 * 64
        int flat = wg*256 + tid;
        int m = flat / 6144; int r = flat % 6144; int s = r >> 6; int d = r & 63;
        const float* W = (m==0)? Wir : (m==1)? Wii : Win;
        const float* B = (m==0)? bir : (m==1)? bii : bin;
        float acc = B[d];
        #pragma unroll 8
        for (int k = 0; k < 64; k++)
            acc += emb[s*64 + k] * W[k*64 + d];
        Ef[flat] = acc;
        if (wg < 5) {
            int c = wg*256 + tid;
            if (c < TSTEP*NTILE) flagv[c] = 0;
        }
    } else {                              // swizzle: 9 * 4096
        int flat = (wg - 72)*256 + tid;
        int m = flat >> 12; int q = flat & 4095;
        int jj = q & 7, lane = (q >> 3) & 63, nt = (q >> 9) & 3, kc = q >> 11;
        int k = kc*32 + ((lane >> 4) << 3) + jj;
        int n = nt*16 + (lane & 15);
        const float* src; int idx = k*64 + n;
        switch (m) {
          case 0: src = Wmsg2; break;
          case 1: src = Whr;  break;
          case 2: src = Whi;  break;
          case 3: src = Whh;  break;
          case 4: src = Wmsg1; break;
          case 5: src = Wmsg1; idx = (64 + k)*64 + n; break;
          case 6: src = Wo1; break;
          case 7: src = Wo2; break;
          default: src = Wo3; break;
        }
        wswz[flat] = (ushort_t)f2bf(src[idx]);
    }
}

// ---------------------------------------------------------------------------
// persistent column kernel: block (b,it) owns its 16-row tile for ALL 12
// steps. 8 waves x 12 j's cover all 96 senders; reduction + GRU are
// block-local (LDS). h lives in LDS the whole time. Cross-block traffic =
// only the S-tile exchange within each 6-block batch group, via the
// R6-proven agent-store/drain/flag protocol (no fences). adj + all weight
// fragments loaded once. grid 96 x 512 threads (co-residency guaranteed).
// ---------------------------------------------------------------------------
__global__ __launch_bounds__(512, 2) void k_all(
    const float* __restrict__ adj, const float* __restrict__ b1in, const float* __restrict__ b2in,
    const int* __restrict__ skills, const float* __restrict__ Ef,
    const ushort_t* __restrict__ wswz,
    float* __restrict__ Sglob, float* __restrict__ hall, int* __restrict__ flagv)
{
    __shared__ float lds[18704];
    float* sAdj = lds;            // 16 x 97 = 1552 (padded stride vs bank conflicts)
    float* sS   = lds + 1552;     // 96 x 64 = 6144
    float* sRB  = lds + 7696;     // 16 x 68 = 1088 (R + b1)
    float* sH   = lds + 8784;     // 16 x 64 = 1024 (resident h tile)
    float* sE   = lds + 9808;     // 192
    float* sAgg = lds + 10000;    // 8 x 1088 = 8704
    float* sM   = sAgg;           // slice 0 (reduced agg, then hnew)
    float* sG   = sAgg + 1088;    // slices 1..3 (gate outputs)

    int wg = blockIdx.x; int b = wg / 6, it = wg % 6;
    int tid = threadIdx.x; int w = tid >> 6; int l = tid & 63;
    int quad = l >> 4, col = l & 15;

    // ---- one-time prelude ----
    for (int q = tid; q < 16*96; q += 512) {
        int i = q / 96, j = q % 96;
        sAdj[i*97 + j] = adj[(b*NN + it*16 + i)*NN + j];
    }
    const short8* wz = (const short8*)wswz;   // matrix 0 = Wmsg2
    short8 w2f[2][4];
    #pragma unroll
    for (int kc = 0; kc < 2; kc++)
      #pragma unroll
      for (int nt = 0; nt < 4; nt++)
        w2f[kc][nt] = wz[(kc*4 + nt)*64 + l];
    float b2v[4], b1v[4];
    #pragma unroll
    for (int nt = 0; nt < 4; nt++) {
        b2v[nt] = b2in[nt*16 + col];
        b1v[nt] = b1in[nt*16 + col];
    }
    short8 fG[8], fSR[8];
    if (w < 3) {
        #pragma unroll
        for (int q = 0; q < 8; q++) fG[q] = wz[(1 + w)*512 + q*64 + l];
    }
    if (w < 2) {
        #pragma unroll
        for (int q = 0; q < 8; q++) fSR[q] = wz[(4 + w)*512 + q*64 + l];
    }
    // t=0 state: S=0, R=0 (sRB=b1), h=0
    for (int q = tid; q < 96*64; q += 512) sS[q] = 0.f;
    for (int q = tid; q < 16*64; q += 512) {
        sRB[(q >> 6)*68 + (q & 63)] = b1in[q & 63];
        sH[q] = 0.f;
    }
    __syncthreads();

    for (int t = 0; t < TSTEP; t++) {
        // ---- message + aggregate: wave w handles j = w*12 + c ----
        float rbv[16];
        #pragma unroll
        for (int c = 0; c < 4; c++)
            *(floatx4*)&rbv[c*4] = *(const floatx4*)&sRB[col*68 + (c>>1)*32 + quad*8 + (c&1)*4];

        float agg[4][4];
        #pragma unroll
        for (int nt=0;nt<4;nt++)
          #pragma unroll
          for (int r=0;r<4;r++) agg[nt][r] = 0.f;

        #pragma unroll 2
        for (int c = 0; c < 12; c++) {
            int jl = w*12 + c;
            float sv[16];
            #pragma unroll
            for (int cc = 0; cc < 4; cc++)
                *(floatx4*)&sv[cc*4] = *(const floatx4*)&sS[jl*64 + (cc>>1)*32 + quad*8 + (cc&1)*4];
            fragU u0, u1;
            #pragma unroll
            for (int e = 0; e < 8; e++) {
                u0.b[e] = (__bf16)fast_tanh(sv[e]   + rbv[e]);
                u1.b[e] = (__bf16)fast_tanh(sv[8+e] + rbv[8+e]);
            }
            floatx4 acc[4];
            zero4(acc);
            #pragma unroll
            for (int nt = 0; nt < 4; nt++) {
                acc[nt] = __builtin_amdgcn_mfma_f32_16x16x32_bf16(u0.s, w2f[0][nt], acc[nt], 0,0,0);
                acc[nt] = __builtin_amdgcn_mfma_f32_16x16x32_bf16(u1.s, w2f[1][nt], acc[nt], 0,0,0);
            }
            float adjv[4];
            #pragma unroll
            for (int r = 0; r < 4; r++) adjv[r] = sAdj[(quad*4 + r)*97 + jl];
            #pragma unroll
            for (int nt = 0; nt < 4; nt++)
              #pragma unroll
              for (int r = 0; r < 4; r++)
                agg[nt][r] += adjv[r] * fast_tanh(acc[nt][r] + b2v[nt]);
        }
        #pragma unroll
        for (int nt = 0; nt < 4; nt++)
          #pragma unroll
          for (int r = 0; r < 4; r++)
            sAgg[w*1088 + (quad*4 + r)*68 + nt*16 + col] = agg[nt][r];
        __syncthreads();

        // ---- reduce 8 slices -> sM (in place, per-thread safe) ; load E rows ----
        if (tid < 256) {
            int i = tid >> 4, k4 = (tid & 15)*4;
            floatx4 a = {0.f,0.f,0.f,0.f};
            #pragma unroll
            for (int s8 = 0; s8 < 8; s8++)
                a += *(const floatx4*)&sAgg[s8*1088 + i*68 + k4];
            a = a * (1.f/96.f);
            *(floatx4*)&sM[i*68 + k4] = a;
        } else if (tid < 448) {
            int q = tid - 256;
            int s = skills[b*13 + t];
            sE[q] = Ef[(q >> 6)*6144 + s*64 + (q & 63)];
        }
        __syncthreads();

        // ---- gate matmuls: wave w -> Whr/Whi/Whh ----
        if (w < 3) {
            short8 a0, a1;
            buildA(sM, col, quad, a0, a1);
            floatx4 acc[4];
            zero4(acc);
            mm16r(a0, a1, fG, acc);
            #pragma unroll
            for (int nt = 0; nt < 4; nt++)
              #pragma unroll
              for (int r = 0; r < 4; r++)
                sG[w*1088 + (quad*4 + r)*68 + nt*16 + col] = acc[nt][r];
        }
        __syncthreads();

        // ---- elementwise GRU: h lives in sH; also store hall[t+1] ----
        if (tid < 256) {
            int i = tid >> 4, k4 = (tid & 15)*4;
            float h[4];
            #pragma unroll
            for (int e = 0; e < 4; e++) {
                int d = k4 + e;
                float gr = fast_sigmoid(sE[d]       + sG[0*1088 + i*68 + d]);
                float gi = fast_sigmoid(sE[64 + d]  + sG[1*1088 + i*68 + d]);
                float nv = fast_tanh  (sE[128 + d] + gr * sG[2*1088 + i*68 + d]);
                h[e] = (1.f - gi)*nv + gi*sH[i*64 + d];
            }
            #pragma unroll
            for (int e = 0; e < 4; e++) {
                sH[i*64 + k4 + e] = h[e];
                sM[i*68 + k4 + e] = h[e];
            }
            floatx4 hv = { h[0], h[1], h[2], h[3] };
            *(floatx4*)&hall[(size_t)(t+1)*HSLOT + (b*NN + it*16 + i)*64 + k4] = hv;
        }
        __syncthreads();
        if (t == TSTEP - 1) break;

        // ---- projections: wave 0 -> S (own tile in sS), wave 1 -> R+b1 (sRB) ----
        if (w < 2) {
            short8 a0, a1;
            buildA(sM, col, quad, a0, a1);
            floatx4 acc[4];
            zero4(acc);
            mm16r(a0, a1, fSR, acc);
            if (w == 0) {
                #pragma unroll
                for (int nt = 0; nt < 4; nt++)
                  #pragma unroll
                  for (int r = 0; r < 4; r++)
                    sS[(it*16 + quad*4 + r)*64 + nt*16 + col] = acc[nt][r];
            } else {
                #pragma unroll
                for (int nt = 0; nt < 4; nt++)
                  #pragma unroll
                  for (int r = 0; r < 4; r++)
                    sRB[(quad*4 + r)*68 + nt*16 + col] = acc[nt][r] + b1v[nt];
            }
        }
        __syncthreads();

        // ---- publish own S tile (agent), drain, set flag ----
        int p = (t + 1) & 1;
        if (tid < 256) {
            int i = tid >> 4, k4 = (tid & 15)*4;
            astore4(&Sglob[(size_t)p*HSLOT + (b*NN + it*16 + i)*64 + k4],
                    *(const floatx4*)&sS[(it*16 + i)*64 + k4]);
        }
        __syncthreads();                  // drains agent stores (vmcnt 0)
        if (tid == 0)
            __hip_atomic_store(&flagv[(t+1)*NTILE + b*ITILES + it], 1,
                               __ATOMIC_RELAXED, __HIP_MEMORY_SCOPE_AGENT);
        // ---- wait for the 5 peer tiles of this batch ----
        if (tid < 6 && tid != it) {
            const int* fp = &flagv[(t+1)*NTILE + b*ITILES + tid];
            while (__hip_atomic_load(fp, __ATOMIC_RELAXED, __HIP_MEMORY_SCOPE_AGENT) == 0)
                __builtin_amdgcn_s_sleep(4);
        }
        __syncthreads();
        // ---- load 5 peer S tiles (agent) ----
        for (int q = tid; q < 1536; q += 512) {
            int tile = q >> 8;
            if (tile == it) continue;
            int idx = q & 255; int i = idx >> 4, k4 = (idx & 15)*4;
            *(floatx4*)&sS[(tile*16 + i)*64 + k4] =
                aload4(&Sglob[(size_t)p*HSLOT + (b*NN + tile*16 + i)*64 + k4]);
        }
        __syncthreads();
    }
}

// ---------------------------------------------------------------------------
// batched output MLP over all steps: 1152 independent 16-row tiles, 4 waves
// per block (one tile each, private LDS slice, no barriers). All tiles read
// hall slots 1..12 (k_all produced h(12) too). grid 288 x 256 threads.
// ---------------------------------------------------------------------------
__global__ __launch_bounds__(256) void k_out(
    const float* __restrict__ hall, const ushort_t* __restrict__ wswz,
    const float* __restrict__ bo1, const float* __restrict__ bo2, const float* __restrict__ bo3,
    float* __restrict__ out)
{
    __shared__ float sT[4][16*68];
    int tid = threadIdx.x; int w = tid >> 6; int l = tid & 63;
    int quad = l >> 4, col = l & 15;
    int g = blockIdx.x*4 + w;
    int ts = g / 96; int rem = g % 96; int b = rem / 6, it = rem % 6;
    float* sm = sT[w];
    {
        const float* hsrc = hall + (size_t)(ts + 1)*HSLOT + (b*NN + it*16)*64;
        int i = l >> 2, c0 = (l & 3)*16;
        #pragma unroll
        for (int cc = 0; cc < 4; cc++)
            *(floatx4*)&sm[i*68 + c0 + cc*4] = *(const floatx4*)&hsrc[i*64 + c0 + cc*4];
    }
    float bv1[4], bv2[4], bv3[4];
    #pragma unroll
    for (int nt = 0; nt < 4; nt++) {
        bv1[nt] = bo1[nt*16 + col];
        bv2[nt] = bo2[nt*16 + col];
        bv3[nt] = bo3[nt*16 + col];
    }
    short8 a0, a1;
    floatx4 acc[4];

    buildA(sm, col, quad, a0, a1);
    zero4(acc);
    mm16(a0, a1, (const short8*)wswz + 6*512, l, acc);
    #pragma unroll
    for (int nt = 0; nt < 4; nt++)
      #pragma unroll
      for (int r = 0; r < 4; r++)
        sm[(quad*4 + r)*68 + nt*16 + col] = fmaxf(0.f, acc[nt][r] + bv1[nt]);

    buildA(sm, col, quad, a0, a1);
    zero4(acc);
    mm16(a0, a1, (const short8*)wswz + 7*512, l, acc);
    #pragma unroll
    for (int nt = 0; nt < 4; nt++)
      #pragma unroll
      for (int r = 0; r < 4; r++)
        sm[(quad*4 + r)*68 + nt*16 + col] = fmaxf(0.f, acc[nt][r] + bv2[nt]);

    buildA(sm, col, quad, a0, a1);
    zero4(acc);
    mm16(a0, a1, (const short8*)wswz + 8*512, l, acc);
    #pragma unroll
    for (int nt = 0; nt < 4; nt++)
      #pragma unroll
      for (int r = 0; r < 4; r++)
        out[((b*TSTEP + ts)*NN + it*16 + quad*4 + r)*64 + nt*16 + col] = acc[nt][r] + bv3[nt];
}

extern "C" void kernel_launch(void* const* d_in, const int* in_sizes, int n_in,
                              void* d_out, int out_size, void* d_ws, size_t ws_size,
                              hipStream_t stream) {
    const int*   skills = (const int*)d_in[0];
    const float* adj    = (const float*)d_in[1];
    const float* emb    = (const float*)d_in[2];
    const float* Wmsg1  = (const float*)d_in[3];
    const float* b1     = (const float*)d_in[4];
    const float* Wmsg2  = (const float*)d_in[5];
    const float* b2     = (const float*)d_in[6];
    const float* Whr    = (const float*)d_in[7];
    const float* Whi    = (const float*)d_in[8];
    const float* Whh    = (const float*)d_in[9];
    const float* Wir    = (const float*)d_in[10];
    const float* bir    = (const float*)d_in[11];
    const float* Wii    = (const float*)d_in[12];
    const float* bii    = (const float*)d_in[13];
    const float* Win    = (const float*)d_in[14];
    const float* bin    = (const float*)d_in[15];
    const float* Wo1    = (const float*)d_in[16];
    const float* bo1    = (const float*)d_in[17];
    const float* Wo2    = (const float*)d_in[18];
    const float* bo2    = (const float*)d_in[19];
    const float* Wo3    = (const float*)d_in[20];
    const float* bo3    = (const float*)d_in[21];

    char* ws = (char*)d_ws;
    float*    hall  = (float*)(ws + OFF_HALL);
    float*    Ef    = (float*)(ws + OFF_E);
    float*    Sglob = (float*)(ws + OFF_SG);
    ushort_t* wswz  = (ushort_t*)(ws + OFF_WSWZ);
    int*      flagv = (int*)(ws + OFF_FLAG);
    float*    out   = (float*)d_out;

    k_init<<<dim3(216), dim3(256), 0, stream>>>(emb, Wmsg1, Wmsg2, Whr, Whi, Whh,
        Wir, bir, Wii, bii, Win, bin, Wo1, Wo2, Wo3, flagv, Ef, wswz);

    k_all<<<dim3(NTILE), dim3(512), 0, stream>>>(
        adj, b1, b2, skills, Ef, wswz, Sglob, hall, flagv);

    k_out<<<dim3(288), dim3(256), 0, stream>>>(hall, wswz, bo1, bo2, bo3, out);
}